// Round 1
// baseline (130.168 us; speedup 1.0000x reference)
//
#include <hip/hip_runtime.h>

// Parametric LIF forward, N=32 T=64 D=32768, fp32.
// h_t = v + k*(x_t - v); s_t = (h_t >= th); v = s ? 0 : h_t.
// k = sigmoid(tau_w[0]) = 0.5 exactly for tau_w=0, so FMA contraction of
// v + k*(x-v) rounds identically to the numpy reference sequence (0.5*t exact).

constexpr int LIF_N  = 32;
constexpr int LIF_T  = 64;
constexpr int LIF_D  = 32768;
constexpr int LIF_D4 = LIF_D / 4;  // 8192 float4 per (n,t) row

__global__ __launch_bounds__(256) void plif_fwd_kernel(
    const float* __restrict__ x,
    const float* __restrict__ tau_w,
    const float* __restrict__ th,
    float* __restrict__ out)
{
    const int tid = blockIdx.x * blockDim.x + threadIdx.x;  // [0, N*D4)
    const int n  = tid >> 13;            // / D4 (8192)
    const int d4 = tid & (LIF_D4 - 1);   // % D4

    const float k   = 1.0f / (1.0f + expf(-tau_w[0]));  // exactly 0.5 for tau_w=0
    const float thv = th[0];

    const float4* __restrict__ xp =
        reinterpret_cast<const float4*>(x) + (size_t)n * LIF_T * LIF_D4 + d4;
    float4* __restrict__ op =
        reinterpret_cast<float4*>(out) + (size_t)n * LIF_T * LIF_D4 + d4;

    float vx = 0.0f, vy = 0.0f, vz = 0.0f, vw = 0.0f;

    #pragma unroll 4
    for (int t = 0; t < LIF_T; ++t) {
        const float4 xt = xp[(size_t)t * LIF_D4];

        const float hx = vx + k * (xt.x - vx);
        const float hy = vy + k * (xt.y - vy);
        const float hz = vz + k * (xt.z - vz);
        const float hw = vw + k * (xt.w - vw);

        // s = (h - th >= 0) == (h >= th) in fp32
        const bool sx = (hx >= thv);
        const bool sy = (hy >= thv);
        const bool sz = (hz >= thv);
        const bool sw = (hw >= thv);

        float4 s;
        s.x = sx ? 1.0f : 0.0f;
        s.y = sy ? 1.0f : 0.0f;
        s.z = sz ? 1.0f : 0.0f;
        s.w = sw ? 1.0f : 0.0f;

        // v_next = h*(1-s) == (s ? 0 : h), exact
        vx = sx ? 0.0f : hx;
        vy = sy ? 0.0f : hy;
        vz = sz ? 0.0f : hz;
        vw = sw ? 0.0f : hw;

        op[(size_t)t * LIF_D4] = s;
    }
}

extern "C" void kernel_launch(void* const* d_in, const int* in_sizes, int n_in,
                              void* d_out, int out_size, void* d_ws, size_t ws_size,
                              hipStream_t stream) {
    const float* x     = (const float*)d_in[0];
    const float* tau_w = (const float*)d_in[1];
    const float* th    = (const float*)d_in[2];
    float* out = (float*)d_out;

    const int total  = LIF_N * LIF_D4;          // 262144 threads
    const int block  = 256;
    const int grid   = total / block;           // 1024 blocks

    plif_fwd_kernel<<<grid, block, 0, stream>>>(x, tau_w, th, out);
}

// Round 2
// 97.208 us; speedup vs baseline: 1.3391x; 1.3391x over previous
//
#include <hip/hip_runtime.h>

// Parametric LIF forward, N=32 T=64 D=32768, fp32.
// h_t = v + k*(x_t - v); s_t = (h_t >= th); v = s ? 0 : h_t.
// k = sigmoid(0) = 0.5 exactly -> FMA contraction rounds identically to ref.
//
// R2: latency-bound fix. float2/thread -> 8192 waves (100% occupancy cap),
// double-buffered G=8 software pipeline (8 loads in flight, decoupled from
// the serial v recurrence), non-temporal load/store (zero reuse; input is
// L3-sized so caching is pure thrash). All reg-array indexing compile-time.

constexpr int LIF_N  = 32;
constexpr int LIF_T  = 64;
constexpr int LIF_D  = 32768;
constexpr int LIF_D2 = LIF_D / 2;   // 16384 float2 per (n,t) row
constexpr int G      = 8;           // pipeline group size (timesteps)
constexpr int NG     = LIF_T / G;   // 8 groups

typedef float f32x2 __attribute__((ext_vector_type(2)));

__global__ __launch_bounds__(256) void plif_fwd_kernel(
    const float* __restrict__ x,
    const float* __restrict__ tau_w,
    const float* __restrict__ th,
    float* __restrict__ out)
{
    const int tid = blockIdx.x * blockDim.x + threadIdx.x;  // [0, N*D2)
    const int n  = tid >> 14;             // / D2 (16384)
    const int d2 = tid & (LIF_D2 - 1);    // % D2

    const float k   = 1.0f / (1.0f + expf(-tau_w[0]));  // exactly 0.5 for tau_w=0
    const float thv = th[0];

    const f32x2* __restrict__ xp =
        reinterpret_cast<const f32x2*>(x) + (size_t)n * LIF_T * LIF_D2 + d2;
    f32x2* __restrict__ op =
        reinterpret_cast<f32x2*>(out) + (size_t)n * LIF_T * LIF_D2 + d2;

    f32x2 bufA[G], bufB[G];

    // Prologue: load group 0 into bufA.
    #pragma unroll
    for (int j = 0; j < G; ++j)
        bufA[j] = __builtin_nontemporal_load(xp + (size_t)j * LIF_D2);

    float vx = 0.0f, vy = 0.0f;

    #pragma unroll
    for (int g = 0; g < NG; ++g) {
        // Compile-time buffer selection (outer loop fully unrolled).
        f32x2* cur = (g & 1) ? bufB : bufA;
        f32x2* nxt = (g & 1) ? bufA : bufB;

        // Prefetch next group (independent of the v-chain below).
        if (g + 1 < NG) {
            #pragma unroll
            for (int j = 0; j < G; ++j)
                nxt[j] = __builtin_nontemporal_load(
                    xp + (size_t)((g + 1) * G + j) * LIF_D2);
        }

        // Compute + store current group.
        #pragma unroll
        for (int j = 0; j < G; ++j) {
            const int t = g * G + j;
            const f32x2 xt = cur[j];

            const float hx = vx + k * (xt.x - vx);
            const float hy = vy + k * (xt.y - vy);

            const bool sx = (hx >= thv);   // == H(h - th) in fp32
            const bool sy = (hy >= thv);

            f32x2 s;
            s.x = sx ? 1.0f : 0.0f;
            s.y = sy ? 1.0f : 0.0f;

            vx = sx ? 0.0f : hx;           // h*(1-s) exact
            vy = sy ? 0.0f : hy;

            __builtin_nontemporal_store(s, op + (size_t)t * LIF_D2);
        }
    }
}

extern "C" void kernel_launch(void* const* d_in, const int* in_sizes, int n_in,
                              void* d_out, int out_size, void* d_ws, size_t ws_size,
                              hipStream_t stream) {
    const float* x     = (const float*)d_in[0];
    const float* tau_w = (const float*)d_in[1];
    const float* th    = (const float*)d_in[2];
    float* out = (float*)d_out;

    const int total = LIF_N * LIF_D2;        // 524288 threads
    const int block = 256;
    const int grid  = total / block;         // 2048 blocks

    plif_fwd_kernel<<<grid, block, 0, stream>>>(x, tau_w, th, out);
}

// Round 3
// 74.828 us; speedup vs baseline: 1.7396x; 1.2991x over previous
//
#include <hip/hip_runtime.h>

// Parametric LIF forward, N=32 T=64 D=32768, fp32.
// h_t = v + k*(x_t - v); s_t = (h_t >= th); v = s ? 0 : h_t.
// k = sigmoid(0) = 0.5 exactly -> FMA contraction rounds identically to ref.
//
// R2: float2/thread (8 waves/SIMD), G=8 double-buffered pipeline. 97 us.
// R3: loads CACHED (input is L3-sized and re-read every graph replay; R1
//     showed FETCH_SIZE = half of input => L3 serves ~50% of reads), stores
//     stay NON-TEMPORAL (write stream must not evict input from L2/L3).

constexpr int LIF_N  = 32;
constexpr int LIF_T  = 64;
constexpr int LIF_D  = 32768;
constexpr int LIF_D2 = LIF_D / 2;   // 16384 float2 per (n,t) row
constexpr int G      = 8;           // pipeline group size (timesteps)
constexpr int NG     = LIF_T / G;   // 8 groups

typedef float f32x2 __attribute__((ext_vector_type(2)));

__global__ __launch_bounds__(256) void plif_fwd_kernel(
    const float* __restrict__ x,
    const float* __restrict__ tau_w,
    const float* __restrict__ th,
    float* __restrict__ out)
{
    const int tid = blockIdx.x * blockDim.x + threadIdx.x;  // [0, N*D2)
    const int n  = tid >> 14;             // / D2 (16384)
    const int d2 = tid & (LIF_D2 - 1);    // % D2

    const float k   = 1.0f / (1.0f + expf(-tau_w[0]));  // exactly 0.5 for tau_w=0
    const float thv = th[0];

    const f32x2* __restrict__ xp =
        reinterpret_cast<const f32x2*>(x) + (size_t)n * LIF_T * LIF_D2 + d2;
    f32x2* __restrict__ op =
        reinterpret_cast<f32x2*>(out) + (size_t)n * LIF_T * LIF_D2 + d2;

    f32x2 bufA[G], bufB[G];

    // Prologue: load group 0 into bufA (cached -- L3 reuse across replays).
    #pragma unroll
    for (int j = 0; j < G; ++j)
        bufA[j] = xp[(size_t)j * LIF_D2];

    float vx = 0.0f, vy = 0.0f;

    #pragma unroll
    for (int g = 0; g < NG; ++g) {
        // Compile-time buffer selection (outer loop fully unrolled).
        f32x2* cur = (g & 1) ? bufB : bufA;
        f32x2* nxt = (g & 1) ? bufA : bufB;

        // Prefetch next group (independent of the v-chain below).
        if (g + 1 < NG) {
            #pragma unroll
            for (int j = 0; j < G; ++j)
                nxt[j] = xp[(size_t)((g + 1) * G + j) * LIF_D2];
        }

        // Compute + store current group.
        #pragma unroll
        for (int j = 0; j < G; ++j) {
            const int t = g * G + j;
            const f32x2 xt = cur[j];

            const float hx = vx + k * (xt.x - vx);
            const float hy = vy + k * (xt.y - vy);

            const bool sx = (hx >= thv);   // == H(h - th) in fp32
            const bool sy = (hy >= thv);

            f32x2 s;
            s.x = sx ? 1.0f : 0.0f;
            s.y = sy ? 1.0f : 0.0f;

            vx = sx ? 0.0f : hx;           // h*(1-s) exact
            vy = sy ? 0.0f : hy;

            __builtin_nontemporal_store(s, op + (size_t)t * LIF_D2);
        }
    }
}

extern "C" void kernel_launch(void* const* d_in, const int* in_sizes, int n_in,
                              void* d_out, int out_size, void* d_ws, size_t ws_size,
                              hipStream_t stream) {
    const float* x     = (const float*)d_in[0];
    const float* tau_w = (const float*)d_in[1];
    const float* th    = (const float*)d_in[2];
    float* out = (float*)d_out;

    const int total = LIF_N * LIF_D2;        // 524288 threads
    const int block = 256;
    const int grid  = total / block;         // 2048 blocks

    plif_fwd_kernel<<<grid, block, 0, stream>>>(x, tau_w, th, out);
}